// Round 9
// baseline (461.113 us; speedup 1.0000x reference)
//
#include <hip/hip_runtime.h>
#include <hip/hip_bf16.h>
#include <math.h>

#define Nn 20480
#define Cc 128
#define Hh 8
#define Ll 4
#define NWw 320
#define BN 81920   // B*N

typedef short sv8 __attribute__((ext_vector_type(8)));
typedef __bf16 bfv8 __attribute__((ext_vector_type(8)));
typedef float f32x4 __attribute__((ext_vector_type(4)));

__device__ __forceinline__ f32x4 mfma16(sv8 a, sv8 b, f32x4 c) {
    return __builtin_amdgcn_mfma_f32_16x16x32_bf16(
        __builtin_bit_cast(bfv8, a), __builtin_bit_cast(bfv8, b), c, 0, 0, 0);
}
__device__ __forceinline__ ushort f2bf(float f) {
    uint u = __float_as_uint(f);
    u += 0x7fffu + ((u >> 16) & 1u);
    return (ushort)(u >> 16);
}
__device__ __forceinline__ uint pk2bf(float lo, float hi) {
    uint r;
    asm("v_cvt_pk_bf16_f32 %0, %1, %2" : "=v"(r) : "v"(lo), "v"(hi));
    return r;
}
__device__ __forceinline__ float fast_gelu(float x) {
    float z = 0.7978845608f * (x + 0.044715f * x * x * x);
    return x * __builtin_amdgcn_rcpf(1.0f + __expf(-2.0f * z));
}

// ---------- stable counting sort of window_ids ----------
__global__ __launch_bounds__(64) void rank_kernel(const int* __restrict__ wid,
        int* __restrict__ lrank, int* __restrict__ hist) {
    __shared__ int keys[64];
    int c = blockIdx.x, lane = threadIdx.x;
    for (int j = lane; j < NWw; j += 64) hist[c * NWw + j] = 0;
    int i = c * 64 + lane;
    int w = wid[i];
    keys[lane] = w;
    __syncthreads();
    int rank = 0, total = 0;
    for (int j = 0; j < 64; ++j) {
        int kj = keys[j];
        total += (kj == w);
        rank += (j < lane && kj == w) ? 1 : 0;
    }
    lrank[i] = rank;
    if (rank == 0) hist[c * NWw + w] = total;
}
__global__ __launch_bounds__(64) void prefix_kernel(int* __restrict__ hist) {
    int w = blockIdx.x, lane = threadIdx.x;
    int running = 0;
    for (int it = 0; it < NWw / 64; ++it) {
        int c = it * 64 + lane;
        int v = hist[c * NWw + w];
        int orig = v;
        #pragma unroll
        for (int d = 1; d < 64; d <<= 1) {
            int tt = __shfl_up(v, d, 64);
            if (lane >= d) v += tt;
        }
        hist[c * NWw + w] = running + v - orig;
        running += __shfl(v, 63, 64);
    }
}
__global__ __launch_bounds__(64) void scatter_kernel(const int* __restrict__ wid,
        const int* __restrict__ lrank, const int* __restrict__ hist,
        int* __restrict__ sidx) {
    int c = blockIdx.x, lane = threadIdx.x;
    int i = c * 64 + lane;
    int w = wid[i];
    sidx[w * 64 + hist[c * NWw + w] + lrank[i]] = i;
}

// ---------- weight convert + transpose to bf16 [N][K] ----------
__global__ __launch_bounds__(256) void wconv_kernel(
    const float* __restrict__ Wqkv, const float* __restrict__ Wproj,
    const float* __restrict__ W1, const float* __restrict__ W2,
    ushort* __restrict__ wt) {
    int id = blockIdx.x * 256 + threadIdx.x;      // < 786432
    int l = id / 196608;
    int r = id % 196608;
    const float* src; int dst;
    if (r < 49152) { int n = r % 384, k = r / 384;
        src = Wqkv + l * 49152 + k * 384 + n; dst = l * 196608 + n * 128 + k; }
    else if (r < 65536) { int rr = r - 49152; int n = rr % 128, k = rr / 128;
        src = Wproj + l * 16384 + k * 128 + n; dst = l * 196608 + 49152 + n * 128 + k; }
    else if (r < 131072) { int rr = r - 65536; int n = rr % 512, k = rr / 512;
        src = W1 + l * 65536 + k * 512 + n; dst = l * 196608 + 65536 + n * 128 + k; }
    else { int rr = r - 131072; int n = rr % 128, k = rr / 128;
        src = W2 + l * 65536 + k * 128 + n; dst = l * 196608 + 131072 + n * 512 + k; }
    wt[dst] = f2bf(*src);
}

// ---------- fused FULL layer: gather+LN1 -> QKV -> attn -> proj+residual(reg)
//            -> LN2(reg, LDS reduce) -> MLP1+gelu -> MLP2 -> +residual -> store
// one block per (batch, window); 256 threads / 4 waves; LDS = 80 KB exactly.
__global__ __launch_bounds__(256, 2) void layer_fused_kernel(
    const float* __restrict__ xsrc, float* __restrict__ xdst,
    const ushort* __restrict__ wqkvT, const float* __restrict__ bqkv,
    const float* __restrict__ relb, const ushort* __restrict__ wprojT,
    const float* __restrict__ bproj, const float* __restrict__ g1,
    const float* __restrict__ be1, const float* __restrict__ g2,
    const float* __restrict__ be2, const ushort* __restrict__ w1T,
    const float* __restrict__ b1, const ushort* __restrict__ w2T,
    const float* __restrict__ b2, const int* __restrict__ sidx) {
    __shared__ __align__(16) ushort hl_[64][128];   // 16 KB: LN1 out / attn out / LN2 out
    __shared__ __align__(16) char arenaB[65536];    // 64 KB: attn bufs, then hid
    // attn-phase views
    ushort* qkn = (ushort*)arenaB;                        // [64][256]  32 KB
    ushort* vT  = (ushort*)(arenaB + 32768);              // [128][72]  18 KB
    ushort* pt  = (ushort*)(arenaB + 51200);              // [4][16][76] 9.5 KB
    int*   ridx = (int*)(arenaB + 60928);                 // 256 B (dies at hid)
    // mlp-phase views
    float* redbuf = (float*)arenaB;                       // [64][4][2] 2 KB
    ushort (*hid)[512] = (ushort (*)[512])arenaB;         // 64 KB

    int t = threadIdx.x;
    int wave = t >> 6, lane = t & 63;
    int lr = lane & 15, lg = lane >> 4;
    int wb = blockIdx.x;
    int bN = (wb / NWw) * Nn;
    int p0 = (wb % NWw) * 64;

    if (t < 64) ridx[t] = sidx[p0 + t];
    __syncthreads();

    // ---- phase 1: gather + LN1 -> hl_
    {
        int hl2 = lane & 31, hb = lane >> 5;
        float4 gg = *(const float4*)(g1 + hl2 * 4);
        float4 bb = *(const float4*)(be1 + hl2 * 4);
        #pragma unroll
        for (int it = 0; it < 8; ++it) {
            int row = it * 8 + wave * 2 + hb;
            int gi = bN + ridx[row];
            float4 v = *(const float4*)(xsrc + (size_t)gi * Cc + hl2 * 4);
            float s = v.x + v.y + v.z + v.w;
            s += __shfl_xor(s, 1, 64);  s += __shfl_xor(s, 2, 64);
            s += __shfl_xor(s, 4, 64);  s += __shfl_xor(s, 8, 64);
            s += __shfl_xor(s, 16, 64);
            float mu = s * 0.0078125f;
            float d0 = v.x - mu, d1 = v.y - mu, d2 = v.z - mu, d3 = v.w - mu;
            float q = d0 * d0 + d1 * d1 + d2 * d2 + d3 * d3;
            q += __shfl_xor(q, 1, 64);  q += __shfl_xor(q, 2, 64);
            q += __shfl_xor(q, 4, 64);  q += __shfl_xor(q, 8, 64);
            q += __shfl_xor(q, 16, 64);
            float rs = rsqrtf(q * 0.0078125f + 1e-5f);
            uint2 pk;
            pk.x = pk2bf(d0 * rs * gg.x + bb.x, d1 * rs * gg.y + bb.y);
            pk.y = pk2bf(d2 * rs * gg.z + bb.z, d3 * rs * gg.w + bb.w);
            *(uint2*)&hl_[row][(hl2 * 4) ^ ((row & 7) << 3)] = pk;
        }
    }
    __syncthreads();

    // ---- phase 2: QKV GEMM; wave computes its own 2 heads' q,k,v
    {
        f32x4 acc[4][6] = {};
        #pragma unroll
        for (int ks = 0; ks < 4; ++ks) {
            int k0 = ks * 32 + lg * 8;
            sv8 a[4], b[6];
            #pragma unroll
            for (int rf = 0; rf < 4; ++rf) {
                int row = rf * 16 + lr;
                a[rf] = *(const sv8*)&hl_[row][k0 ^ ((row & 7) << 3)];
            }
            #pragma unroll
            for (int nf = 0; nf < 6; ++nf) {
                int gcol = (nf < 2 ? 32 * wave + nf * 16
                          : nf < 4 ? 128 + 32 * wave + (nf - 2) * 16
                                   : 256 + 32 * wave + (nf - 4) * 16) + lr;
                b[nf] = *(const sv8*)(wqkvT + (size_t)gcol * 128 + k0);
            }
            #pragma unroll
            for (int rf = 0; rf < 4; ++rf)
                #pragma unroll
                for (int nf = 0; nf < 6; ++nf)
                    acc[rf][nf] = mfma16(a[rf], b[nf], acc[rf][nf]);
        }
        #pragma unroll
        for (int nf = 0; nf < 6; ++nf) {
            int gcol = (nf < 2 ? 32 * wave + nf * 16
                      : nf < 4 ? 128 + 32 * wave + (nf - 2) * 16
                               : 256 + 32 * wave + (nf - 4) * 16) + lr;
            float bs = bqkv[gcol];
            if (nf < 4) {
                #pragma unroll
                for (int rf = 0; rf < 4; ++rf)
                    #pragma unroll
                    for (int r = 0; r < 4; ++r) {
                        int row = rf * 16 + lg * 4 + r;
                        qkn[row * 256 + (gcol ^ ((row & 7) << 3))] = f2bf(acc[rf][nf][r] + bs);
                    }
            } else {
                int dcol = gcol - 256;
                #pragma unroll
                for (int rf = 0; rf < 4; ++rf) {
                    uint2 pk;
                    pk.x = pk2bf(acc[rf][nf][0] + bs, acc[rf][nf][1] + bs);
                    pk.y = pk2bf(acc[rf][nf][2] + bs, acc[rf][nf][3] + bs);
                    *(uint2*)&vT[dcol * 72 + rf * 16 + lg * 4] = pk;
                }
            }
        }
    }
    __syncthreads();

    // ---- phase 3: attention (swapped QK^T), 2 heads per wave; out -> hl_
    f32x4 zz = {0.f, 0.f, 0.f, 0.f};
    #pragma unroll
    for (int hi = 0; hi < 2; ++hi) {
        int hh = wave * 2 + hi;
        float rb = relb[hh];
        sv8 bv[2];
        #pragma unroll
        for (int ks = 0; ks < 2; ++ks)
            bv[ks] = *(const sv8*)&vT[(hh * 16 + lr) * 72 + ks * 32 + lg * 8];
        sv8 aq[4], bk[4];
        sv8 z = {0, 0, 0, 0, 0, 0, 0, 0};
        bool lo = (lg < 2);
        #pragma unroll
        for (int f = 0; f < 4; ++f) {
            aq[f] = z; bk[f] = z;
            if (lo) {
                int row = f * 16 + lr;
                aq[f] = *(const sv8*)&qkn[row * 256 + ((hh * 16 + lg * 8) ^ ((row & 7) << 3))];
                bk[f] = *(const sv8*)&qkn[row * 256 + ((128 + hh * 16 + lg * 8) ^ ((row & 7) << 3))];
            }
        }
        f32x4 s[4][4];
        #pragma unroll
        for (int kt = 0; kt < 4; ++kt)
            #pragma unroll
            for (int qt = 0; qt < 4; ++qt)
                s[kt][qt] = mfma16(bk[kt], aq[qt], zz);

        f32x4 o[4];
        ushort* ptw = pt + wave * 16 * 76;
        #pragma unroll
        for (int qt = 0; qt < 4; ++qt) {
            float v[16];
            #pragma unroll
            for (int kt = 0; kt < 4; ++kt)
                #pragma unroll
                for (int r = 0; r < 4; ++r)
                    v[kt * 4 + r] = s[kt][qt][r] * 0.25f + rb;
            float m0 = fmaxf(fmaxf(fmaxf(v[0], v[1]), fmaxf(v[2], v[3])),
                             fmaxf(fmaxf(v[4], v[5]), fmaxf(v[6], v[7])));
            float m1 = fmaxf(fmaxf(fmaxf(v[8], v[9]), fmaxf(v[10], v[11])),
                             fmaxf(fmaxf(v[12], v[13]), fmaxf(v[14], v[15])));
            float mx = fmaxf(m0, m1);
            mx = fmaxf(mx, __shfl_xor(mx, 16, 64));
            mx = fmaxf(mx, __shfl_xor(mx, 32, 64));
            float sum = 0.f;
            #pragma unroll
            for (int i = 0; i < 16; ++i) {
                v[i] = __expf(v[i] - mx);
                sum += v[i];
            }
            sum += __shfl_xor(sum, 16, 64);
            sum += __shfl_xor(sum, 32, 64);
            float inv = __builtin_amdgcn_rcpf(sum);
            #pragma unroll
            for (int kt = 0; kt < 4; ++kt) {
                uint2 pk;
                pk.x = pk2bf(v[kt * 4 + 0] * inv, v[kt * 4 + 1] * inv);
                pk.y = pk2bf(v[kt * 4 + 2] * inv, v[kt * 4 + 3] * inv);
                *(uint2*)&ptw[lr * 76 + kt * 16 + lg * 4] = pk;
            }
            sv8 ap0 = *(const sv8*)&ptw[lr * 76 + lg * 8];
            sv8 ap1 = *(const sv8*)&ptw[lr * 76 + 32 + lg * 8];
            o[qt] = mfma16(ap0, bv[0], zz);
            o[qt] = mfma16(ap1, bv[1], o[qt]);
        }
        #pragma unroll
        for (int qt = 0; qt < 4; ++qt)
            #pragma unroll
            for (int r = 0; r < 4; ++r) {
                int row = qt * 16 + lg * 4 + r;
                hl_[row][(hh * 16 + lr) ^ ((row & 7) << 3)] = f2bf(o[qt][r]);
            }
    }
    __syncthreads();

    // ---- phase 4: proj + bias + residual -> acc_x (registers)
    f32x4 acc_x[4][2] = {};
    {
        #pragma unroll
        for (int ks = 0; ks < 4; ++ks) {
            int k0 = ks * 32 + lg * 8;
            sv8 a[4], b[2];
            #pragma unroll
            for (int rf = 0; rf < 4; ++rf) {
                int row = rf * 16 + lr;
                a[rf] = *(const sv8*)&hl_[row][k0 ^ ((row & 7) << 3)];
            }
            #pragma unroll
            for (int nf = 0; nf < 2; ++nf)
                b[nf] = *(const sv8*)(wprojT + (size_t)(wave * 32 + nf * 16 + lr) * 128 + k0);
            #pragma unroll
            for (int rf = 0; rf < 4; ++rf)
                #pragma unroll
                for (int nf = 0; nf < 2; ++nf)
                    acc_x[rf][nf] = mfma16(a[rf], b[nf], acc_x[rf][nf]);
        }
        #pragma unroll
        for (int nf = 0; nf < 2; ++nf) {
            int col = wave * 32 + nf * 16 + lr;
            float bs = bproj[col];
            #pragma unroll
            for (int rf = 0; rf < 4; ++rf)
                #pragma unroll
                for (int r = 0; r < 4; ++r) {
                    int row = rf * 16 + lg * 4 + r;
                    int gi = bN + ridx[row];
                    acc_x[rf][nf][r] += xsrc[(size_t)gi * Cc + col] + bs;
                }
        }
    }
    // ---- phase 5a: per-wave row partials (sum, sumsq) -> redbuf
    {
        #pragma unroll
        for (int rf = 0; rf < 4; ++rf)
            #pragma unroll
            for (int r = 0; r < 4; ++r) {
                float s = acc_x[rf][0][r] + acc_x[rf][1][r];
                float q = acc_x[rf][0][r] * acc_x[rf][0][r] + acc_x[rf][1][r] * acc_x[rf][1][r];
                s += __shfl_xor(s, 1, 64);  q += __shfl_xor(q, 1, 64);
                s += __shfl_xor(s, 2, 64);  q += __shfl_xor(q, 2, 64);
                s += __shfl_xor(s, 4, 64);  q += __shfl_xor(q, 4, 64);
                s += __shfl_xor(s, 8, 64);  q += __shfl_xor(q, 8, 64);
                if (lr == 0) {
                    int row = rf * 16 + lg * 4 + r;
                    redbuf[(row * 4 + wave) * 2 + 0] = s;
                    redbuf[(row * 4 + wave) * 2 + 1] = q;
                }
            }
    }
    __syncthreads();
    // ---- phase 5b: LN2 normalize in-register -> hl_ (bf16 swizzled)
    {
        float g2a[2], be2a[2];
        #pragma unroll
        for (int nf = 0; nf < 2; ++nf) {
            int col = wave * 32 + nf * 16 + lr;
            g2a[nf] = g2[col];
            be2a[nf] = be2[col];
        }
        #pragma unroll
        for (int rf = 0; rf < 4; ++rf)
            #pragma unroll
            for (int r = 0; r < 4; ++r) {
                int row = rf * 16 + lg * 4 + r;
                float s = redbuf[(row * 4 + 0) * 2] + redbuf[(row * 4 + 1) * 2]
                        + redbuf[(row * 4 + 2) * 2] + redbuf[(row * 4 + 3) * 2];
                float q = redbuf[(row * 4 + 0) * 2 + 1] + redbuf[(row * 4 + 1) * 2 + 1]
                        + redbuf[(row * 4 + 2) * 2 + 1] + redbuf[(row * 4 + 3) * 2 + 1];
                float mu = s * 0.0078125f;
                float var = q * 0.0078125f - mu * mu;
                float rs = rsqrtf(var + 1e-5f);
                #pragma unroll
                for (int nf = 0; nf < 2; ++nf) {
                    int col = wave * 32 + nf * 16 + lr;
                    float xh = (acc_x[rf][nf][r] - mu) * rs * g2a[nf] + be2a[nf];
                    hl_[row][col ^ ((row & 7) << 3)] = f2bf(xh);
                }
            }
    }
    __syncthreads();   // hl_ ready; redbuf dead -> hid may take over arenaB

    // ---- phase 6: MLP1 + gelu -> hid (two halves of 64 cols/wave to cap VGPR)
    #pragma unroll
    for (int hf2 = 0; hf2 < 2; ++hf2) {
        f32x4 acc[4][4] = {};
        #pragma unroll
        for (int ks = 0; ks < 4; ++ks) {
            int k0 = ks * 32 + lg * 8;
            sv8 a[4], b[4];
            #pragma unroll
            for (int rf = 0; rf < 4; ++rf) {
                int row = rf * 16 + lr;
                a[rf] = *(const sv8*)&hl_[row][k0 ^ ((row & 7) << 3)];
            }
            #pragma unroll
            for (int nf = 0; nf < 4; ++nf)
                b[nf] = *(const sv8*)(w1T + (size_t)(wave * 128 + hf2 * 64 + nf * 16 + lr) * 128 + k0);
            #pragma unroll
            for (int rf = 0; rf < 4; ++rf)
                #pragma unroll
                for (int nf = 0; nf < 4; ++nf)
                    acc[rf][nf] = mfma16(a[rf], b[nf], acc[rf][nf]);
        }
        #pragma unroll
        for (int nf = 0; nf < 4; ++nf) {
            int col = wave * 128 + hf2 * 64 + nf * 16 + lr;
            float bs = b1[col];
            #pragma unroll
            for (int rf = 0; rf < 4; ++rf)
                #pragma unroll
                for (int r = 0; r < 4; ++r) {
                    int row = rf * 16 + lg * 4 + r;
                    hid[row][col ^ ((row & 7) << 3)] = f2bf(fast_gelu(acc[rf][nf][r] + bs));
                }
        }
    }
    __syncthreads();

    // ---- phase 7: MLP2 (K=512) + residual(acc_x) -> store to xdst (scattered rows)
    {
        f32x4 acc2[4][2] = {};
        #pragma unroll
        for (int ks = 0; ks < 16; ++ks) {
            int k0 = ks * 32 + lg * 8;
            sv8 a[4], b[2];
            #pragma unroll
            for (int rf = 0; rf < 4; ++rf) {
                int row = rf * 16 + lr;
                a[rf] = *(const sv8*)&hid[row][k0 ^ ((row & 7) << 3)];
            }
            #pragma unroll
            for (int nf = 0; nf < 2; ++nf)
                b[nf] = *(const sv8*)(w2T + (size_t)(wave * 32 + nf * 16 + lr) * 512 + k0);
            #pragma unroll
            for (int rf = 0; rf < 4; ++rf)
                #pragma unroll
                for (int nf = 0; nf < 2; ++nf)
                    acc2[rf][nf] = mfma16(a[rf], b[nf], acc2[rf][nf]);
        }
        #pragma unroll
        for (int nf = 0; nf < 2; ++nf) {
            int col = wave * 32 + nf * 16 + lr;
            float bs = b2[col];
            #pragma unroll
            for (int rf = 0; rf < 4; ++rf)
                #pragma unroll
                for (int r = 0; r < 4; ++r) {
                    int row = rf * 16 + lg * 4 + r;
                    int gi = bN + sidx[p0 + row];   // ridx region overlaid by hid
                    xdst[(size_t)gi * Cc + col] = acc_x[rf][nf][r] + acc2[rf][nf][r] + bs;
                }
        }
    }
}

extern "C" void kernel_launch(void* const* d_in, const int* in_sizes, int n_in,
                              void* d_out, int out_size, void* d_ws, size_t ws_size,
                              hipStream_t stream) {
    const float* x_in   = (const float*)d_in[0];
    const float* g1     = (const float*)d_in[1];
    const float* be1    = (const float*)d_in[2];
    const float* Wqkv   = (const float*)d_in[3];
    const float* bqkv   = (const float*)d_in[4];
    const float* relb   = (const float*)d_in[5];
    const float* Wproj  = (const float*)d_in[6];
    const float* bproj  = (const float*)d_in[7];
    const float* g2     = (const float*)d_in[8];
    const float* be2    = (const float*)d_in[9];
    const float* W1     = (const float*)d_in[10];
    const float* b1     = (const float*)d_in[11];
    const float* W2     = (const float*)d_in[12];
    const float* b2     = (const float*)d_in[13];
    const int*   wid    = (const int*)d_in[14];

    size_t off = 0;
    float* x_ws = (float*)d_ws;                      off += (size_t)BN * Cc * 4;
    ushort* wt  = (ushort*)((char*)d_ws + off);      off += (size_t)786432 * 2;
    int* sidx   = (int*)((char*)d_ws + off);         off += (size_t)Nn * 4;
    int* lrank  = (int*)((char*)d_ws + off);         off += (size_t)Nn * 4;
    int* hist   = (int*)((char*)d_ws + off);         off += (size_t)NWw * NWw * 4;
    if (ws_size < off) return;

    rank_kernel<<<Nn / 64, 64, 0, stream>>>(wid, lrank, hist);
    prefix_kernel<<<NWw, 64, 0, stream>>>(hist);
    scatter_kernel<<<Nn / 64, 64, 0, stream>>>(wid, lrank, hist, sidx);
    wconv_kernel<<<786432 / 256, 256, 0, stream>>>(Wqkv, Wproj, W1, W2, wt);

    for (int l = 0; l < Ll; ++l) {
        const ushort* wqkvT  = wt + (size_t)l * 196608;
        const ushort* wprojT = wqkvT + 49152;
        const ushort* w1T    = wqkvT + 65536;
        const ushort* w2T    = wqkvT + 131072;
        const float* xsrc = (l == 0) ? x_in : x_ws;
        float* xdst = (l == Ll - 1) ? (float*)d_out : x_ws;

        layer_fused_kernel<<<BN / 64, 256, 0, stream>>>(
            xsrc, xdst, wqkvT, bqkv + l * 384, relb + l * Hh,
            wprojT, bproj + l * Cc, g1 + l * Cc, be1 + l * Cc,
            g2 + l * Cc, be2 + l * Cc, w1T, b1 + l * 512,
            w2T, b2 + l * Cc, sidx);
    }
}